// Round 4
// baseline (222.950 us; speedup 1.0000x reference)
//
#include <hip/hip_runtime.h>

// Problem constants (from reference): B=16, T=512, D=8576.
#define N_ROWS 8192            // B*T
#define D_CH   8576
#define DV     (D_CH / 4)      // 2144 float4 columns
#define STATS_ROWS_PER_BLOCK 32
#define STATS_ROW_CHUNKS (N_ROWS / STATS_ROWS_PER_BLOCK)   // 256
#define APPLY_ROWS_PER_BLOCK 8
#define APPLY_ROW_CHUNKS (N_ROWS / APPLY_ROWS_PER_BLOCK)   // 1024
#define EPSV 1e-5f
#define NOISE_STD 0.05f

typedef float f32x4 __attribute__((ext_vector_type(4)));

// ws layout (floats): [0,D) sum | [D,2D) sumsq | [2D,3D) scale | [3D,4D) shift

__global__ __launch_bounds__(256) void bn_partial_stats(
    const f32x4* __restrict__ x, float* __restrict__ ws_sum, float* __restrict__ ws_sq)
{
    int vc = blockIdx.x * blockDim.x + threadIdx.x;   // vec-channel
    if (vc >= DV) return;
    size_t base = (size_t)blockIdx.y * STATS_ROWS_PER_BLOCK * DV + vc;
    // four independent accumulator pairs; 4 loads issued per group for MLP
    f32x4 s0 = (f32x4)0.f, s1 = (f32x4)0.f, s2 = (f32x4)0.f, s3 = (f32x4)0.f;
    f32x4 q0 = (f32x4)0.f, q1 = (f32x4)0.f, q2 = (f32x4)0.f, q3 = (f32x4)0.f;
#pragma unroll 2
    for (int r = 0; r < STATS_ROWS_PER_BLOCK; r += 4) {
        f32x4 a = x[base + (size_t)(r + 0) * DV];
        f32x4 b = x[base + (size_t)(r + 1) * DV];
        f32x4 c = x[base + (size_t)(r + 2) * DV];
        f32x4 d = x[base + (size_t)(r + 3) * DV];
        s0 += a; q0 += a * a;
        s1 += b; q1 += b * b;
        s2 += c; q2 += c * c;
        s3 += d; q3 += d * d;
    }
    f32x4 s = (s0 + s1) + (s2 + s3);
    f32x4 q = (q0 + q1) + (q2 + q3);
    int d0 = vc * 4;
    atomicAdd(&ws_sum[d0 + 0], s.x);
    atomicAdd(&ws_sum[d0 + 1], s.y);
    atomicAdd(&ws_sum[d0 + 2], s.z);
    atomicAdd(&ws_sum[d0 + 3], s.w);
    atomicAdd(&ws_sq[d0 + 0], q.x);
    atomicAdd(&ws_sq[d0 + 1], q.y);
    atomicAdd(&ws_sq[d0 + 2], q.z);
    atomicAdd(&ws_sq[d0 + 3], q.w);
}

__global__ __launch_bounds__(256) void bn_finalize(
    const float* __restrict__ ws_sum, const float* __restrict__ ws_sq,
    const float* __restrict__ gamma, const float* __restrict__ beta,
    float* __restrict__ ws_scale, float* __restrict__ ws_shift)
{
    int d = blockIdx.x * blockDim.x + threadIdx.x;
    if (d >= D_CH) return;
    const float invN = 1.0f / (float)N_ROWS;
    float mu  = ws_sum[d] * invN;
    float var = ws_sq[d] * invN - mu * mu;
    float sc  = gamma[d] * rsqrtf(var + EPSV);
    ws_scale[d] = sc;
    ws_shift[d] = beta[d] - mu * sc;
}

__global__ __launch_bounds__(256) void bn_apply(
    const f32x4* __restrict__ x, const f32x4* __restrict__ noise,
    const f32x4* __restrict__ ws_scale4, const f32x4* __restrict__ ws_shift4,
    f32x4* __restrict__ out)
{
    int vc = blockIdx.x * blockDim.x + threadIdx.x;
    if (vc >= DV) return;
    f32x4 sc = ws_scale4[vc];
    f32x4 sh = ws_shift4[vc];
    size_t base = (size_t)blockIdx.y * APPLY_ROWS_PER_BLOCK * DV + vc;
#pragma unroll 8
    for (int r = 0; r < APPLY_ROWS_PER_BLOCK; ++r) {
        size_t idx = base + (size_t)r * DV;
        f32x4 xv = x[idx];                                    // cached: L3-resident from stats pass
        f32x4 nv = __builtin_nontemporal_load(&noise[idx]);   // stream once, don't evict x
        f32x4 o = xv * sc + sh + nv * NOISE_STD;
        __builtin_nontemporal_store(o, &out[idx]);            // never re-read, don't pollute L3
    }
}

extern "C" void kernel_launch(void* const* d_in, const int* in_sizes, int n_in,
                              void* d_out, int out_size, void* d_ws, size_t ws_size,
                              hipStream_t stream) {
    const float* x     = (const float*)d_in[0];
    const float* noise = (const float*)d_in[1];
    const float* gamma = (const float*)d_in[2];
    const float* beta  = (const float*)d_in[3];
    float* out = (float*)d_out;

    float* ws       = (float*)d_ws;
    float* ws_sum   = ws;
    float* ws_sq    = ws + D_CH;
    float* ws_scale = ws + 2 * D_CH;
    float* ws_shift = ws + 3 * D_CH;

    // Zero the accumulators (stream-ordered, capture-safe).
    (void)hipMemsetAsync(d_ws, 0, 2 * D_CH * sizeof(float), stream);

    dim3 blk(256, 1, 1);
    dim3 grd_stats((DV + 255) / 256, STATS_ROW_CHUNKS, 1);   // 9 x 256
    bn_partial_stats<<<grd_stats, blk, 0, stream>>>((const f32x4*)x, ws_sum, ws_sq);

    dim3 grd_fin((D_CH + 255) / 256, 1, 1);                  // 34
    bn_finalize<<<grd_fin, blk, 0, stream>>>(ws_sum, ws_sq, gamma, beta, ws_scale, ws_shift);

    dim3 grd_apply((DV + 255) / 256, APPLY_ROW_CHUNKS, 1);   // 9 x 1024
    bn_apply<<<grd_apply, blk, 0, stream>>>((const f32x4*)x, (const f32x4*)noise,
                                            (const f32x4*)ws_scale, (const f32x4*)ws_shift,
                                            (f32x4*)out);
}

// Round 5
// 221.261 us; speedup vs baseline: 1.0076x; 1.0076x over previous
//
#include <hip/hip_runtime.h>

// Problem constants (from reference): B=16, T=512, D=8576.
#define N_ROWS 8192            // B*T
#define D_CH   8576
#define DV     (D_CH / 4)      // 2144 float4 columns
#define STATS_ROWS_PER_BLOCK 32
#define STATS_ROW_CHUNKS (N_ROWS / STATS_ROWS_PER_BLOCK)   // 256
#define APPLY_ROWS_PER_BLOCK 16
#define APPLY_ROW_CHUNKS (N_ROWS / APPLY_ROWS_PER_BLOCK)   // 512
#define EPSV 1e-5f
#define NOISE_STD 0.05f

typedef float f32x4 __attribute__((ext_vector_type(4)));

// ws layout (floats): [0,D) sum | [D,2D) sumsq | [2D,3D) scale | [3D,4D) shift

__global__ __launch_bounds__(256) void bn_partial_stats(
    const f32x4* __restrict__ x, float* __restrict__ ws_sum, float* __restrict__ ws_sq)
{
    int vc = blockIdx.x * blockDim.x + threadIdx.x;   // vec-channel
    if (vc >= DV) return;
    size_t base = (size_t)blockIdx.y * STATS_ROWS_PER_BLOCK * DV + vc;
    f32x4 s0 = (f32x4)0.f, s1 = (f32x4)0.f, s2 = (f32x4)0.f, s3 = (f32x4)0.f;
    f32x4 q0 = (f32x4)0.f, q1 = (f32x4)0.f, q2 = (f32x4)0.f, q3 = (f32x4)0.f;
    // 4 iterations; each batch-issues 8 independent loads before consuming.
#pragma unroll
    for (int r = 0; r < STATS_ROWS_PER_BLOCK; r += 8) {
        f32x4 v0 = x[base + (size_t)(r + 0) * DV];
        f32x4 v1 = x[base + (size_t)(r + 1) * DV];
        f32x4 v2 = x[base + (size_t)(r + 2) * DV];
        f32x4 v3 = x[base + (size_t)(r + 3) * DV];
        f32x4 v4 = x[base + (size_t)(r + 4) * DV];
        f32x4 v5 = x[base + (size_t)(r + 5) * DV];
        f32x4 v6 = x[base + (size_t)(r + 6) * DV];
        f32x4 v7 = x[base + (size_t)(r + 7) * DV];
        s0 += v0; q0 += v0 * v0;
        s1 += v1; q1 += v1 * v1;
        s2 += v2; q2 += v2 * v2;
        s3 += v3; q3 += v3 * v3;
        s0 += v4; q0 += v4 * v4;
        s1 += v5; q1 += v5 * v5;
        s2 += v6; q2 += v6 * v6;
        s3 += v7; q3 += v7 * v7;
    }
    f32x4 s = (s0 + s1) + (s2 + s3);
    f32x4 q = (q0 + q1) + (q2 + q3);
    int d0 = vc * 4;
    atomicAdd(&ws_sum[d0 + 0], s.x);
    atomicAdd(&ws_sum[d0 + 1], s.y);
    atomicAdd(&ws_sum[d0 + 2], s.z);
    atomicAdd(&ws_sum[d0 + 3], s.w);
    atomicAdd(&ws_sq[d0 + 0], q.x);
    atomicAdd(&ws_sq[d0 + 1], q.y);
    atomicAdd(&ws_sq[d0 + 2], q.z);
    atomicAdd(&ws_sq[d0 + 3], q.w);
}

__global__ __launch_bounds__(256) void bn_finalize(
    const float* __restrict__ ws_sum, const float* __restrict__ ws_sq,
    const float* __restrict__ gamma, const float* __restrict__ beta,
    float* __restrict__ ws_scale, float* __restrict__ ws_shift)
{
    int d = blockIdx.x * blockDim.x + threadIdx.x;
    if (d >= D_CH) return;
    const float invN = 1.0f / (float)N_ROWS;
    float mu  = ws_sum[d] * invN;
    float var = ws_sq[d] * invN - mu * mu;
    float sc  = gamma[d] * rsqrtf(var + EPSV);
    ws_scale[d] = sc;
    ws_shift[d] = beta[d] - mu * sc;
}

__global__ __launch_bounds__(256) void bn_apply(
    const f32x4* __restrict__ x, const f32x4* __restrict__ noise,
    const f32x4* __restrict__ ws_scale4, const f32x4* __restrict__ ws_shift4,
    f32x4* __restrict__ out)
{
    int vc = blockIdx.x * blockDim.x + threadIdx.x;
    if (vc >= DV) return;
    f32x4 sc = ws_scale4[vc];
    f32x4 sh = ws_shift4[vc];
    size_t base = (size_t)blockIdx.y * APPLY_ROWS_PER_BLOCK * DV + vc;
    // Two half-batches of 8 rows: 16 loads in flight, then 8 computes+stores.
#pragma unroll
    for (int h = 0; h < 2; ++h) {
        size_t b = base + (size_t)(h * 8) * DV;
        f32x4 xv[8], nv[8];
#pragma unroll
        for (int r = 0; r < 8; ++r) xv[r] = x[b + (size_t)r * DV];                                  // cached: L3-resident
#pragma unroll
        for (int r = 0; r < 8; ++r) nv[r] = __builtin_nontemporal_load(&noise[b + (size_t)r * DV]); // stream once
#pragma unroll
        for (int r = 0; r < 8; ++r) {
            f32x4 o = xv[r] * sc + sh + nv[r] * NOISE_STD;
            __builtin_nontemporal_store(o, &out[b + (size_t)r * DV]);                               // never re-read
        }
    }
}

extern "C" void kernel_launch(void* const* d_in, const int* in_sizes, int n_in,
                              void* d_out, int out_size, void* d_ws, size_t ws_size,
                              hipStream_t stream) {
    const float* x     = (const float*)d_in[0];
    const float* noise = (const float*)d_in[1];
    const float* gamma = (const float*)d_in[2];
    const float* beta  = (const float*)d_in[3];
    float* out = (float*)d_out;

    float* ws       = (float*)d_ws;
    float* ws_sum   = ws;
    float* ws_sq    = ws + D_CH;
    float* ws_scale = ws + 2 * D_CH;
    float* ws_shift = ws + 3 * D_CH;

    // Zero the accumulators (stream-ordered, capture-safe).
    (void)hipMemsetAsync(d_ws, 0, 2 * D_CH * sizeof(float), stream);

    dim3 blk(256, 1, 1);
    dim3 grd_stats((DV + 255) / 256, STATS_ROW_CHUNKS, 1);   // 9 x 256
    bn_partial_stats<<<grd_stats, blk, 0, stream>>>((const f32x4*)x, ws_sum, ws_sq);

    dim3 grd_fin((D_CH + 255) / 256, 1, 1);                  // 34
    bn_finalize<<<grd_fin, blk, 0, stream>>>(ws_sum, ws_sq, gamma, beta, ws_scale, ws_shift);

    dim3 grd_apply((DV + 255) / 256, APPLY_ROW_CHUNKS, 1);   // 9 x 512
    bn_apply<<<grd_apply, blk, 0, stream>>>((const f32x4*)x, (const f32x4*)noise,
                                            (const f32x4*)ws_scale, (const f32x4*)ws_shift,
                                            (f32x4*)out);
}